// Round 2
// baseline (207.818 us; speedup 1.0000x reference)
//
#include <hip/hip_runtime.h>
#include <hip/hip_bf16.h>

typedef __bf16 bf16_t;
typedef __bf16 bf16x8 __attribute__((ext_vector_type(8)));
typedef __bf16 bf16x4 __attribute__((ext_vector_type(4)));
typedef float  f32x4  __attribute__((ext_vector_type(4)));

static __device__ __forceinline__ f32x4 mfma16(bf16x8 a, bf16x8 b, f32x4 c) {
    return __builtin_amdgcn_mfma_f32_16x16x32_bf16(a, b, c, 0, 0, 0);
}

// ---------------------------------------------------------------------------
// Pack W1 edge rows [128..160) and W2 [256x256] into bf16 MFMA fragment order:
// frag[(tile16)*64 + lane][j] = W[8*(lane>>4)+j + 32*kstep][ct*16 + (lane&15)]
// (same layout serves as A- or B-fragment: index16 = lane&15, k = 8*(lane>>4)+j)
// ---------------------------------------------------------------------------
__global__ void prep_pack(const float* __restrict__ W1, const float* __restrict__ W2,
                          bf16_t* __restrict__ W1ef, bf16_t* __restrict__ W2f) {
    int t = blockIdx.x * blockDim.x + threadIdx.x;
    int l = t & 63;
    int g = l >> 4;
    int c = l & 15;
    if (t < 1024) {                       // W1 edge part: 16 col-tiles x 64 lanes
        int ct = t >> 6;
        #pragma unroll
        for (int j = 0; j < 8; ++j)
            W1ef[t * 8 + j] = (bf16_t)W1[(128 + 8 * g + j) * 256 + ct * 16 + c];
    } else if (t < 1024 + 8192) {         // W2: 8 ksteps x 16 col-tiles x 64 lanes
        int t2 = t - 1024;
        int ks = t2 >> 10;
        int ct = (t2 >> 6) & 15;
        #pragma unroll
        for (int j = 0; j < 8; ++j)
            W2f[t2 * 8 + j] = (bf16_t)W2[(ks * 32 + 8 * g + j) * 256 + ct * 16 + c];
    }
}

// ---------------------------------------------------------------------------
// Pi[b,i,h] = nodes[b,i,:] @ W1[0:128,h] + b1[h]   (f32)
// Pj[b,j,h] = nodes[b,j,:] @ W1[160:288,h]         (f32, temp)
// ---------------------------------------------------------------------------
__global__ __launch_bounds__(256) void prep_pij(const float* __restrict__ nodes,
                                                const float* __restrict__ W1,
                                                const float* __restrict__ b1,
                                                float* __restrict__ Pi,
                                                float* __restrict__ Pj) {
    int b = blockIdx.x >> 2;
    int q = blockIdx.x & 3;
    int h = threadIdx.x;
    const float* nb = nodes + (b * 64 + q * 16) * 128;
    float ai[16], aj[16];
    float bias = b1[h];
    #pragma unroll
    for (int ii = 0; ii < 16; ++ii) { ai[ii] = bias; aj[ii] = 0.f; }
    for (int d = 0; d < 128; ++d) {
        float wi = W1[d * 256 + h];
        float wj = W1[(160 + d) * 256 + h];
        #pragma unroll
        for (int ii = 0; ii < 16; ++ii) {
            float s = nb[ii * 128 + d];
            ai[ii] = fmaf(s, wi, ai[ii]);
            aj[ii] = fmaf(s, wj, aj[ii]);
        }
    }
    #pragma unroll
    for (int ii = 0; ii < 16; ++ii) {
        Pi[(b * 64 + q * 16 + ii) * 256 + h] = ai[ii];
        Pj[(b * 64 + q * 16 + ii) * 256 + h] = aj[ii];
    }
}

// ---------------------------------------------------------------------------
// Repack Pj f32 [128][64][256] -> Pjf bf16, fragment-linear per batch:
// unit U(j,h) = ((j>>4)*8 + (h>>5))*64 + ((h>>3)&3)*16 + (j&15); elem e = h&7
// -> unit U holds Pj[j][ks*32 + q*8 + (0..7)] : 8 contiguous h. 2048 units/b.
// ---------------------------------------------------------------------------
__global__ __launch_bounds__(256) void prep_pjf(const float* __restrict__ Pj,
                                                bf16_t* __restrict__ Pjf) {
    int u = blockIdx.x * 256 + threadIdx.x;     // 128 * 2048 units
    int b = u >> 11, u2 = u & 2047;
    int pt = u2 >> 9, ks = (u2 >> 6) & 7, q = (u2 >> 4) & 3, c = u2 & 15;
    int j = pt * 16 + c, h0 = ks * 32 + q * 8;
    const float* src = Pj + ((long)(b * 64 + j)) * 256 + h0;
    f32x4 v0 = *(const f32x4*)src;
    f32x4 v1 = *(const f32x4*)(src + 4);
    bf16x8 o;
    #pragma unroll
    for (int e = 0; e < 4; ++e) { o[e] = (bf16_t)v0[e]; o[4 + e] = (bf16_t)v1[e]; }
    *(bf16x8*)(Pjf + (long)u * 8) = o;
}

// ---------------------------------------------------------------------------
// Main fused MLP. Block = 64 pairs (one source node i, all 64 j). 8 waves.
// L1 (swapped operands): D'[h][pair]; wave w owns h in [32w, 32w+32).
// a1f: fragment-linear bf16 in LDS (L2 A-frag reads are lane-linear, 0-conflict)
// L2: wave w computes all 64 rows x cols [32w, 32w+32).
// ---------------------------------------------------------------------------
__global__ __launch_bounds__(512, 4) void mlp_main(
    const float* __restrict__ edges,
    const float* __restrict__ Pi, const bf16_t* __restrict__ Pjf,
    const bf16_t* __restrict__ W1ef, const bf16_t* __restrict__ W2f,
    const float* __restrict__ b2, const float* __restrict__ W3,
    const float* __restrict__ b3, float* __restrict__ out) {

    __shared__ bf16_t a1f[2048 * 8];      // 32 KB, fragment-linear 16B units
    __shared__ float part[8][64];

    const int orig = blockIdx.x;
    const int blk = (orig & 7) * 1024 + (orig >> 3);  // XCD swizzle (8192 % 8 == 0)
    const int b = blk >> 6, i = blk & 63;
    const int tid = threadIdx.x;
    const int w = tid >> 6;               // wave 0..7
    const int l = tid & 63;
    const int g = l >> 4, c = l & 15;

    const long ebase = ((long)b * 4096 + i * 64) * 32;

    // ---------------- layer 1 (swapped): A=W1e^T frags, B=edge frags ----------
    const f32x4 z4 = {0.f, 0.f, 0.f, 0.f};
    f32x4 acc1[2][4];                     // [ht'][pt]
    #pragma unroll
    for (int ht = 0; ht < 2; ++ht)
        #pragma unroll
        for (int pt = 0; pt < 4; ++pt) acc1[ht][pt] = z4;

    bf16x8 wf[2];
    #pragma unroll
    for (int ht = 0; ht < 2; ++ht)
        wf[ht] = *(const bf16x8*)&W1ef[((w * 2 + ht) * 64 + l) * 8];

    #pragma unroll
    for (int pt = 0; pt < 4; ++pt) {
        const float* ep = edges + ebase + (pt * 16 + c) * 32 + 8 * g;
        f32x4 e0 = *(const f32x4*)ep;
        f32x4 e1 = *(const f32x4*)(ep + 4);
        bf16x8 ef;
        #pragma unroll
        for (int j = 0; j < 4; ++j) { ef[j] = (bf16_t)e0[j]; ef[4 + j] = (bf16_t)e1[j]; }
        #pragma unroll
        for (int ht = 0; ht < 2; ++ht)
            acc1[ht][pt] = mfma16(wf[ht], ef, acc1[ht][pt]);
    }

    // epilogue: + Pi + Pj, relu, pack bf16x4, one ds_write_b64 per fragment
    {
        const float* PiB = Pi + ((long)blk) * 256 + w * 32;     // blk = b*64+i
        f32x4 piv[2];
        #pragma unroll
        for (int ht = 0; ht < 2; ++ht)
            piv[ht] = *(const f32x4*)(PiB + ht * 16 + 4 * g);
        const bf16_t* PjB = Pjf + (long)b * 16384;
        #pragma unroll
        for (int pt = 0; pt < 4; ++pt) {
            #pragma unroll
            for (int ht = 0; ht < 2; ++ht) {
                int U = (pt * 8 + w) * 64 + (2 * ht + (g >> 1)) * 16 + c;
                int off = U * 8 + 4 * (g & 1);
                bf16x4 pj = *(const bf16x4*)(PjB + off);
                bf16x4 o;
                #pragma unroll
                for (int r = 0; r < 4; ++r) {
                    float v = acc1[ht][pt][r] + piv[ht][r] + (float)pj[r];
                    v = v > 0.f ? v : 0.f;
                    o[r] = (bf16_t)v;
                }
                *(bf16x4*)(&a1f[off]) = o;
            }
        }
    }
    __syncthreads();

    // ---------------- layer 2: rows 64 (4 rt), cols [32w, 32w+32) (2 ct) ------
    f32x4 acc2[4][2];
    #pragma unroll
    for (int rt = 0; rt < 4; ++rt)
        #pragma unroll
        for (int ct = 0; ct < 2; ++ct) acc2[rt][ct] = z4;

    #pragma unroll
    for (int ks = 0; ks < 8; ++ks) {
        bf16x8 bfr[2], af[4];
        #pragma unroll
        for (int ct = 0; ct < 2; ++ct)
            bfr[ct] = *(const bf16x8*)&W2f[((ks * 16 + w * 2 + ct) * 64 + l) * 8];
        #pragma unroll
        for (int rt = 0; rt < 4; ++rt)
            af[rt] = *(const bf16x8*)&a1f[((rt * 8 + ks) * 64 + l) * 8];
        #pragma unroll
        for (int rt = 0; rt < 4; ++rt)
            #pragma unroll
            for (int ct = 0; ct < 2; ++ct)
                acc2[rt][ct] = mfma16(af[rt], bfr[ct], acc2[rt][ct]);
    }

    // ---------------- layer 3: relu(a2 + b2) @ W3, reduce ---------------------
    float b2v[2], w3v[2];
    #pragma unroll
    for (int ct = 0; ct < 2; ++ct) {
        int h2 = w * 32 + ct * 16 + c;
        b2v[ct] = b2[h2];
        w3v[ct] = W3[h2];
    }

    #pragma unroll
    for (int rt = 0; rt < 4; ++rt) {
        #pragma unroll
        for (int r = 0; r < 4; ++r) {
            float s = 0.f;
            #pragma unroll
            for (int ct = 0; ct < 2; ++ct) {
                float v = acc2[rt][ct][r] + b2v[ct];
                v = v > 0.f ? v : 0.f;
                s = fmaf(v, w3v[ct], s);
            }
            s += __shfl_xor(s, 1);
            s += __shfl_xor(s, 2);
            s += __shfl_xor(s, 4);
            s += __shfl_xor(s, 8);
            if (c == 0) part[w][rt * 16 + 4 * g + r] = s;
        }
    }
    __syncthreads();

    if (tid < 64) {
        float s = b3[0];
        #pragma unroll
        for (int ww = 0; ww < 8; ++ww) s += part[ww][tid];
        out[(long)blk * 64 + tid] = s;
    }
}

extern "C" void kernel_launch(void* const* d_in, const int* in_sizes, int n_in,
                              void* d_out, int out_size, void* d_ws, size_t ws_size,
                              hipStream_t stream) {
    const float* nodes = (const float*)d_in[0];
    const float* edges = (const float*)d_in[1];
    const float* W1    = (const float*)d_in[2];
    const float* b1    = (const float*)d_in[3];
    const float* W2    = (const float*)d_in[4];
    const float* b2    = (const float*)d_in[5];
    const float* W3    = (const float*)d_in[6];
    const float* b3    = (const float*)d_in[7];
    float* out = (float*)d_out;

    char* ws = (char*)d_ws;
    float*  Pi   = (float*)ws;                                        // 8 MB
    float*  Pj   = (float*)(ws + (size_t)8 * 1024 * 1024);            // 8 MB (temp)
    bf16_t* Pjf  = (bf16_t*)(ws + (size_t)16 * 1024 * 1024);          // 4 MB
    bf16_t* W2f  = (bf16_t*)(ws + (size_t)20 * 1024 * 1024);          // 128 KB
    bf16_t* W1ef = (bf16_t*)(ws + (size_t)20 * 1024 * 1024 + 131072); // 16 KB

    prep_pack<<<dim3(36), dim3(256), 0, stream>>>(W1, W2, W1ef, W2f);
    prep_pij<<<dim3(512), dim3(256), 0, stream>>>(nodes, W1, b1, Pi, Pj);
    prep_pjf<<<dim3(1024), dim3(256), 0, stream>>>(Pj, Pjf);
    mlp_main<<<dim3(8192), dim3(512), 0, stream>>>(edges, Pi, Pjf, W1ef, W2f, b2, W3, b3, out);
}

// Round 3
// 196.313 us; speedup vs baseline: 1.0586x; 1.0586x over previous
//
#include <hip/hip_runtime.h>
#include <hip/hip_bf16.h>

typedef __bf16 bf16_t;
typedef __bf16 bf16x8 __attribute__((ext_vector_type(8)));
typedef __bf16 bf16x4 __attribute__((ext_vector_type(4)));
typedef float  f32x4  __attribute__((ext_vector_type(4)));

static __device__ __forceinline__ f32x4 mfma16(bf16x8 a, bf16x8 b, f32x4 c) {
    return __builtin_amdgcn_mfma_f32_16x16x32_bf16(a, b, c, 0, 0, 0);
}

// ---------------------------------------------------------------------------
// Pack W1 edge rows [128..160) and W2 [256x256] into bf16 MFMA fragment order:
// frag[(tile16)*64 + lane][j] = W[8*(lane>>4)+j + 32*kstep][ct*16 + (lane&15)]
// ---------------------------------------------------------------------------
__global__ void prep_pack(const float* __restrict__ W1, const float* __restrict__ W2,
                          bf16_t* __restrict__ W1ef, bf16_t* __restrict__ W2f) {
    int t = blockIdx.x * blockDim.x + threadIdx.x;
    int l = t & 63;
    int g = l >> 4;
    int c = l & 15;
    if (t < 1024) {                       // W1 edge part
        int ct = t >> 6;
        #pragma unroll
        for (int j = 0; j < 8; ++j)
            W1ef[t * 8 + j] = (bf16_t)W1[(128 + 8 * g + j) * 256 + ct * 16 + c];
    } else if (t < 1024 + 8192) {         // W2
        int t2 = t - 1024;
        int ks = t2 >> 10;
        int ct = (t2 >> 6) & 15;
        #pragma unroll
        for (int j = 0; j < 8; ++j)
            W2f[t2 * 8 + j] = (bf16_t)W2[(ks * 32 + 8 * g + j) * 256 + ct * 16 + c];
    }
}

// ---------------------------------------------------------------------------
// Pi[b,i,h] = nodes[b,i,:] @ W1[0:128,h] + b1[h]   (f32)
// Pj[b,j,h] = nodes[b,j,:] @ W1[160:288,h]         (f32, temp)
// ---------------------------------------------------------------------------
__global__ __launch_bounds__(256) void prep_pij(const float* __restrict__ nodes,
                                                const float* __restrict__ W1,
                                                const float* __restrict__ b1,
                                                float* __restrict__ Pi,
                                                float* __restrict__ Pj) {
    int b = blockIdx.x >> 2;
    int q = blockIdx.x & 3;
    int h = threadIdx.x;
    const float* nb = nodes + (b * 64 + q * 16) * 128;
    float ai[16], aj[16];
    float bias = b1[h];
    #pragma unroll
    for (int ii = 0; ii < 16; ++ii) { ai[ii] = bias; aj[ii] = 0.f; }
    for (int d = 0; d < 128; ++d) {
        float wi = W1[d * 256 + h];
        float wj = W1[(160 + d) * 256 + h];
        #pragma unroll
        for (int ii = 0; ii < 16; ++ii) {
            float s = nb[ii * 128 + d];
            ai[ii] = fmaf(s, wi, ai[ii]);
            aj[ii] = fmaf(s, wj, aj[ii]);
        }
    }
    #pragma unroll
    for (int ii = 0; ii < 16; ++ii) {
        Pi[(b * 64 + q * 16 + ii) * 256 + h] = ai[ii];
        Pj[(b * 64 + q * 16 + ii) * 256 + h] = aj[ii];
    }
}

// ---------------------------------------------------------------------------
// Repack Pj f32 -> Pjf bf16 fragment-linear per batch (verified layout, R2).
// ---------------------------------------------------------------------------
__global__ __launch_bounds__(256) void prep_pjf(const float* __restrict__ Pj,
                                                bf16_t* __restrict__ Pjf) {
    int u = blockIdx.x * 256 + threadIdx.x;
    int b = u >> 11, u2 = u & 2047;
    int pt = u2 >> 9, ks = (u2 >> 6) & 7, q = (u2 >> 4) & 3, c = u2 & 15;
    int j = pt * 16 + c, h0 = ks * 32 + q * 8;
    const float* src = Pj + ((long)(b * 64 + j)) * 256 + h0;
    f32x4 v0 = *(const f32x4*)src;
    f32x4 v1 = *(const f32x4*)(src + 4);
    bf16x8 o;
    #pragma unroll
    for (int e = 0; e < 4; ++e) { o[e] = (bf16_t)v0[e]; o[4 + e] = (bf16_t)v1[e]; }
    *(bf16x8*)(Pjf + (long)u * 8) = o;
}

// ---------------------------------------------------------------------------
// Persistent fused MLP: 1024 blocks x 8 chunks of 64 pairs. 8 waves = 8
// col-groups. W2/W1e/Pjf fragments hoisted to registers; edges+Pi prefetched
// one chunk ahead; double-buffered a1f + part; ONE barrier per chunk.
// ---------------------------------------------------------------------------
__global__ __launch_bounds__(512, 2) void mlp_main(
    const float* __restrict__ edges,
    const float* __restrict__ Pi, const bf16_t* __restrict__ Pjf,
    const bf16_t* __restrict__ W1ef, const bf16_t* __restrict__ W2f,
    const float* __restrict__ b2, const float* __restrict__ W3,
    const float* __restrict__ b3, float* __restrict__ out) {

    __shared__ bf16_t a1f[2][16384];      // 2 x 32 KB fragment-linear
    __shared__ float part[2][8][64];      // 2 x 2 KB partial sums

    const int p = blockIdx.x;
    const int xb = (p & 7) * 128 + (p >> 3);   // XCD swizzle (1024 % 8 == 0)
    const long cbase = (long)xb * 8;           // first of 8 consecutive chunks
    const int b = xb >> 3;                     // batch constant across chunks
    const int tid = threadIdx.x;
    const int w = tid >> 6, l = tid & 63, g = l >> 4, c = l & 15;

    // ---- hoisted invariants (registers for the whole block lifetime) ----
    bf16x8 wf[2];
    #pragma unroll
    for (int ht = 0; ht < 2; ++ht)
        wf[ht] = *(const bf16x8*)&W1ef[((w * 2 + ht) * 64 + l) * 8];

    bf16x8 bfr[8][2];                     // 64 VGPRs of W2 fragments
    #pragma unroll
    for (int ks = 0; ks < 8; ++ks)
        #pragma unroll
        for (int ct = 0; ct < 2; ++ct)
            bfr[ks][ct] = *(const bf16x8*)&W2f[((ks * 16 + w * 2 + ct) * 64 + l) * 8];

    int offA[4][2];
    bf16x4 pj[4][2];                      // Pjf depends only on b -> hoist
    {
        const bf16_t* PjB = Pjf + (long)b * 16384;
        #pragma unroll
        for (int pt = 0; pt < 4; ++pt)
            #pragma unroll
            for (int ht = 0; ht < 2; ++ht) {
                int U = (pt * 8 + w) * 64 + (2 * ht + (g >> 1)) * 16 + c;
                offA[pt][ht] = U * 8 + 4 * (g & 1);
                pj[pt][ht] = *(const bf16x4*)(PjB + offA[pt][ht]);
            }
    }

    float b2v[2], w3v[2];
    #pragma unroll
    for (int ct = 0; ct < 2; ++ct) {
        int h2 = w * 32 + ct * 16 + c;
        b2v[ct] = b2[h2];
        w3v[ct] = W3[h2];
    }
    const float bias3 = b3[0];

    const float* ebase = edges + cbase * 2048 + (long)c * 32 + 8 * g;

    f32x4 e0[4], e1[4];                   // edge prefetch registers
    f32x4 piv[2];                         // Pi prefetch registers

    auto LOADE = [&](int t) {
        const float* ep = ebase + (long)t * 2048;
        #pragma unroll
        for (int pt = 0; pt < 4; ++pt) {
            e0[pt] = *(const f32x4*)(ep + pt * 512);
            e1[pt] = *(const f32x4*)(ep + pt * 512 + 4);
        }
    };
    auto LOADP = [&](int t) {
        const float* pp = Pi + (cbase + t) * 256 + w * 32 + 4 * g;
        piv[0] = *(const f32x4*)pp;
        piv[1] = *(const f32x4*)(pp + 16);
    };

    auto L1PHASE = [&](bf16_t* abuf) {    // layer 1 for the chunk in e/piv regs
        const f32x4 z4 = {0.f, 0.f, 0.f, 0.f};
        f32x4 acc1[2][4];
        #pragma unroll
        for (int ht = 0; ht < 2; ++ht)
            #pragma unroll
            for (int pt = 0; pt < 4; ++pt) acc1[ht][pt] = z4;
        bf16x8 ef[4];
        #pragma unroll
        for (int pt = 0; pt < 4; ++pt) {
            #pragma unroll
            for (int j2 = 0; j2 < 4; ++j2) {
                ef[pt][j2]     = (bf16_t)e0[pt][j2];
                ef[pt][4 + j2] = (bf16_t)e1[pt][j2];
            }
        }
        #pragma unroll
        for (int pt = 0; pt < 4; ++pt)
            #pragma unroll
            for (int ht = 0; ht < 2; ++ht)
                acc1[ht][pt] = mfma16(wf[ht], ef[pt], acc1[ht][pt]);
        #pragma unroll
        for (int pt = 0; pt < 4; ++pt)
            #pragma unroll
            for (int ht = 0; ht < 2; ++ht) {
                bf16x4 o;
                #pragma unroll
                for (int r = 0; r < 4; ++r) {
                    float v = acc1[ht][pt][r] + piv[ht][r] + (float)pj[pt][ht][r];
                    v = v > 0.f ? v : 0.f;
                    o[r] = (bf16_t)v;
                }
                *(bf16x4*)(abuf + offA[pt][ht]) = o;
            }
    };

    auto L2PHASE = [&](const bf16_t* abuf, float* pbuf) {
        const f32x4 z4 = {0.f, 0.f, 0.f, 0.f};
        f32x4 acc2[4][2];
        #pragma unroll
        for (int rt = 0; rt < 4; ++rt)
            #pragma unroll
            for (int ct = 0; ct < 2; ++ct) acc2[rt][ct] = z4;
        #pragma unroll
        for (int ks = 0; ks < 8; ++ks) {
            bf16x8 af[4];
            #pragma unroll
            for (int rt = 0; rt < 4; ++rt)
                af[rt] = *(const bf16x8*)(abuf + ((rt * 8 + ks) * 64 + l) * 8);
            #pragma unroll
            for (int rt = 0; rt < 4; ++rt)
                #pragma unroll
                for (int ct = 0; ct < 2; ++ct)
                    acc2[rt][ct] = mfma16(af[rt], bfr[ks][ct], acc2[rt][ct]);
        }
        #pragma unroll
        for (int rt = 0; rt < 4; ++rt)
            #pragma unroll
            for (int r = 0; r < 4; ++r) {
                float s = 0.f;
                #pragma unroll
                for (int ct = 0; ct < 2; ++ct) {
                    float v = acc2[rt][ct][r] + b2v[ct];
                    v = v > 0.f ? v : 0.f;
                    s = fmaf(v, w3v[ct], s);
                }
                s += __shfl_xor(s, 1);
                s += __shfl_xor(s, 2);
                s += __shfl_xor(s, 4);
                s += __shfl_xor(s, 8);
                if (c == 0) pbuf[rt * 16 + 4 * g + r] = s;
            }
    };

    // ---- prologue: chunk 0 through layer 1 ----
    LOADE(0); LOADP(0);
    L1PHASE(&a1f[0][0]);
    __syncthreads();

    // ---- steady state: one barrier per chunk ----
    #pragma unroll 2
    for (int t = 0; t < 8; ++t) {
        if (t < 7) { LOADE(t + 1); LOADP(t + 1); }   // in flight across L2 phase
        if (t > 0 && tid < 64) {                     // deferred out for chunk t-1
            float s = bias3;
            #pragma unroll
            for (int ww = 0; ww < 8; ++ww) s += part[(t - 1) & 1][ww][tid];
            out[(cbase + t - 1) * 64 + tid] = s;
        }
        L2PHASE(&a1f[t & 1][0], &part[t & 1][w][0]);
        if (t < 7) L1PHASE(&a1f[(t + 1) & 1][0]);
        __syncthreads();
    }
    if (tid < 64) {                                  // out for chunk 7
        float s = bias3;
        #pragma unroll
        for (int ww = 0; ww < 8; ++ww) s += part[1][ww][tid];
        out[(cbase + 7) * 64 + tid] = s;
    }
}

extern "C" void kernel_launch(void* const* d_in, const int* in_sizes, int n_in,
                              void* d_out, int out_size, void* d_ws, size_t ws_size,
                              hipStream_t stream) {
    const float* nodes = (const float*)d_in[0];
    const float* edges = (const float*)d_in[1];
    const float* W1    = (const float*)d_in[2];
    const float* b1    = (const float*)d_in[3];
    const float* W2    = (const float*)d_in[4];
    const float* b2    = (const float*)d_in[5];
    const float* W3    = (const float*)d_in[6];
    const float* b3    = (const float*)d_in[7];
    float* out = (float*)d_out;

    char* ws = (char*)d_ws;
    float*  Pi   = (float*)ws;                                        // 8 MB
    float*  Pj   = (float*)(ws + (size_t)8 * 1024 * 1024);            // 8 MB (temp)
    bf16_t* Pjf  = (bf16_t*)(ws + (size_t)16 * 1024 * 1024);          // 4 MB
    bf16_t* W2f  = (bf16_t*)(ws + (size_t)20 * 1024 * 1024);          // 128 KB
    bf16_t* W1ef = (bf16_t*)(ws + (size_t)20 * 1024 * 1024 + 131072); // 16 KB

    prep_pack<<<dim3(36), dim3(256), 0, stream>>>(W1, W2, W1ef, W2f);
    prep_pij<<<dim3(512), dim3(256), 0, stream>>>(nodes, W1, b1, Pi, Pj);
    prep_pjf<<<dim3(1024), dim3(256), 0, stream>>>(Pj, Pjf);
    mlp_main<<<dim3(1024), dim3(512), 0, stream>>>(edges, Pi, Pjf, W1ef, W2f, b2, W3, b3, out);
}